// Round 10
// baseline (64.198 us; speedup 1.0000x reference)
//
#include <hip/hip_runtime.h>

// B=64, D=256, M=100
//   k(b,i,j) = sum_m sign(f_i)sign(f_j)min(|f_i|,|f_j|) * exp(T)   [0.5 absorbed]
//   out = k - rowmean_i - rowmean_j (symmetric), triu-packed per batch.
// ONE kernel, 640 blocks. Each block: compute full-M 64x64 tile (fdot2 packed
// fp16), stash acc in LDS (f16), write row/col partials to ws, per-batch
// counter barrier (nothing live in VGPRs across the spin -> no round-7/8
// spill), then reload from LDS, center via slot_enc row-sum gather, triu-pack.

#define NB 64
#define DD 256
#define MM 100
#define TILE 64
#define NUT 10                 // upper 64x64 tile-pairs of the 4x4 tile grid
#define TRI_PER_B 32896        // D*(D+1)/2
#define NTILE 640              // NB * NUT
#define NM2 50                 // fp16x2 m-pairs (full M)

typedef unsigned int u32;
typedef _Float16 f16x2 __attribute__((ext_vector_type(2)));

__device__ __forceinline__ void tile_coords(int t, int& ti, int& tj) {
    int a = (t >= 4) + (t >= 7) + (t >= 9);
    int s = (a * (9 - a)) >> 1;   // 0,4,7,9
    ti = a;
    tj = t - s + a;
}

// For row-group g, the 4 (ut, side) slots covering its row sums.
// byte = ut | (side<<5): g0:{0A,1A,2A,3A} g1:{4A,5A,6A,1B} g2:{7A,8A,2B,5B} g3:{9A,3B,6B,8B}
__device__ __forceinline__ u32 slot_enc(int g) {
    return g == 0 ? 0x03020100u : g == 1 ? 0x21060504u
         : g == 2 ? 0x25220807u : 0x28262309u;
}

// XCD-aware swizzle: XCD x gets 80 consecutive tiles = 8 whole batches.
__device__ __forceinline__ int swz_bt(int w) { return (w & 7) * 80 + (w >> 3); }

extern "C" __global__ void __launch_bounds__(256, 4)
k_fused(const float* __restrict__ f, const float* __restrict__ temp,
        float* __restrict__ part, u32* __restrict__ ctr,
        float* __restrict__ out) {
    __shared__ u32 As[NM2][TILE];   // 12.8 KB
    __shared__ u32 Bs[NM2][TILE];   // 12.8 KB
    const int t = threadIdx.x;
    const int bt = swz_bt(blockIdx.x);   // 0..639
    const int b = bt / NUT;
    const int ut = bt % NUT;
    int ti, tj;
    tile_coords(ut, ti, tj);
    const int i0 = ti * TILE, j0 = tj * TILE;
    const float* fb = f + (size_t)b * DD * MM;

    // ---- stage full M as packed fp16, layout [m2][row] ----
    for (int l = t; l < TILE * 25; l += 256) {   // 1600 float4 per matrix
        const int il = l & 63;
        const int mq = l >> 6;                   // 0..24
        float4 v = *reinterpret_cast<const float4*>(fb + (size_t)(i0 + il) * MM + mq * 4);
        As[2 * mq + 0][il] = __builtin_bit_cast(u32, __builtin_amdgcn_cvt_pkrtz(v.x, v.y));
        As[2 * mq + 1][il] = __builtin_bit_cast(u32, __builtin_amdgcn_cvt_pkrtz(v.z, v.w));
        float4 w = *reinterpret_cast<const float4*>(fb + (size_t)(j0 + il) * MM + mq * 4);
        Bs[2 * mq + 0][il] = __builtin_bit_cast(u32, __builtin_amdgcn_cvt_pkrtz(w.x, w.y));
        Bs[2 * mq + 1][il] = __builtin_bit_cast(u32, __builtin_amdgcn_cvt_pkrtz(w.z, w.w));
    }
    __syncthreads();

    const int tix = t & 15, tiy = t >> 4;   // row group / col group
    float acc[4][4] = {};

    #pragma unroll 5
    for (int m2 = 0; m2 < NM2; ++m2) {
        uint4 afu = *reinterpret_cast<const uint4*>(&As[m2][tix * 4]);
        uint4 bfu = *reinterpret_cast<const uint4*>(&Bs[m2][tiy * 4]);
        const u32 av[4] = {afu.x, afu.y, afu.z, afu.w};
        const u32 bv[4] = {bfu.x, bfu.y, bfu.z, bfu.w};
        u32 aab[4], aso[4], bab[4], bsg[4];
        #pragma unroll
        for (int q = 0; q < 4; ++q) {
            aab[q] = av[q] & 0x7fff7fffu;                 // |a|
            aso[q] = (av[q] & 0x80008000u) | 0x3c003c00u; // +-1.0 w/ a's sign
        }
        #pragma unroll
        for (int r = 0; r < 4; ++r) {
            bab[r] = bv[r] & 0x7fff7fffu;                 // |b|
            bsg[r] = bv[r] & 0x80008000u;                 // b's sign
        }
        #pragma unroll
        for (int q = 0; q < 4; ++q) {
            #pragma unroll
            for (int r = 0; r < 4; ++r) {
                u32 so = aso[q] ^ bsg[r];                 // +-1.0 product sign
                f16x2 mn = __builtin_elementwise_min(
                    __builtin_bit_cast(f16x2, aab[q]),
                    __builtin_bit_cast(f16x2, bab[r]));   // v_pk_min_f16
                acc[q][r] = __builtin_amdgcn_fdot2(
                    mn, __builtin_bit_cast(f16x2, so), acc[q][r], false);
            }
        }
    }

    // row/col partial sums (registers)
    float ra[4], cb[4];
    #pragma unroll
    for (int q = 0; q < 4; ++q)
        ra[q] = (acc[q][0] + acc[q][1]) + (acc[q][2] + acc[q][3]);
    #pragma unroll
    for (int r = 0; r < 4; ++r)
        cb[r] = (acc[0][r] + acc[1][r]) + (acc[2][r] + acc[3][r]);

    __syncthreads();                       // staging reads done; reuse LDS
    float* red   = reinterpret_cast<float*>(&As[0][0]);   // [16][64]
    float* red2  = red + 1024;                            // [16][64]
    u32*   stash = &Bs[0][0];                             // [8][256] f16x2
    #pragma unroll
    for (int q = 0; q < 4; ++q) red[tiy * 64 + tix * 4 + q] = ra[q];
    #pragma unroll
    for (int r = 0; r < 4; ++r) red2[tix * 64 + tiy * 4 + r] = cb[r];
    // stash acc tile as f16 (LDS survives the wait; VGPRs go dead -> no spill)
    #pragma unroll
    for (int q = 0; q < 4; ++q) {
        stash[(2 * q + 0) * 256 + t] =
            __builtin_bit_cast(u32, __builtin_amdgcn_cvt_pkrtz(acc[q][0], acc[q][1]));
        stash[(2 * q + 1) * 256 + t] =
            __builtin_bit_cast(u32, __builtin_amdgcn_cvt_pkrtz(acc[q][2], acc[q][3]));
    }
    __syncthreads();

    const size_t pbase = (size_t)bt * 128;
    if (t < TILE) {
        float s = 0.f;
        #pragma unroll
        for (int w = 0; w < 16; ++w) s += red[w * 64 + t];
        part[pbase + t] = s;                       // side 0 (rows i0..)
    } else if (t < 2 * TILE && ti != tj) {
        const int u = t - TILE;
        float s = 0.f;
        #pragma unroll
        for (int w = 0; w < 16; ++w) s += red2[w * 64 + u];
        part[pbase + 64 + u] = s;                  // side 1 (rows j0..)
    }
    __syncthreads();            // barrier drains vmcnt: part stores in flight done

    // ---- per-batch arrival + wait (nothing live in VGPRs here) ----
    if (t == 0) {
        __threadfence();                           // release: part visible
        atomicAdd(&ctr[b], 1u);
        while (atomicAdd(&ctr[b], 0u) < NUT)
            __builtin_amdgcn_s_sleep(2);
        __threadfence();                           // acquire
    }
    __syncthreads();

    // ---- finalize own tile: transposed mapping for coalesced triu stores ----
    const int ftix = t >> 4, ftiy = t & 15;        // row group / col group
    const int to = ((t & 15) << 4) | (t >> 4);     // owner thread of this subtile

    // rebuild the 128 row sums this tile needs (4 slot-loads each)
    float* rows_sh = red;                          // reuse (red consumed)
    if (t < 128) {
        const int half = t >> 6, u = t & 63;
        const int g = half ? tj : ti;
        const u32 enc = slot_enc(g);
        float sum = 0.f;
        #pragma unroll
        for (int s = 0; s < 4; ++s) {
            const u32 byte = (enc >> (8 * s)) & 0xffu;
            const int ut_s = byte & 0x1f;
            const int side = byte >> 5;
            sum += part[(size_t)(b * NUT + ut_s) * 128 + side * 64 + u];
        }
        rows_sh[t] = sum;
    }
    __syncthreads();

    float vv[4][4];
    #pragma unroll
    for (int q = 0; q < 4; ++q) {
        f16x2 w0 = __builtin_bit_cast(f16x2, stash[(2 * q + 0) * 256 + to]);
        f16x2 w1 = __builtin_bit_cast(f16x2, stash[(2 * q + 1) * 256 + to]);
        vv[q][0] = (float)w0.x; vv[q][1] = (float)w0.y;
        vv[q][2] = (float)w1.x; vv[q][3] = (float)w1.y;
    }

    const float scale = expf(temp[0]);   // 0.5 absorbed by sign-min identity
    const float inv_d = 1.0f / DD;
    const int cbase = (ti == tj) ? 0 : 64;
    float rloc[4], cloc[4];
    #pragma unroll
    for (int q = 0; q < 4; ++q) rloc[q] = rows_sh[ftix * 4 + q];
    #pragma unroll
    for (int r = 0; r < 4; ++r) cloc[r] = rows_sh[cbase + ftiy * 4 + r];

    float* ob = out + (size_t)b * TRI_PER_B;
    #pragma unroll
    for (int q = 0; q < 4; ++q) {
        const int i = i0 + ftix * 4 + q;
        float v[4];
        #pragma unroll
        for (int r = 0; r < 4; ++r)
            v[r] = scale * (vv[q][r] - (rloc[q] + cloc[r]) * inv_d);
        const int j0e = j0 + ftiy * 4;
        if (ti != tj) {
            const int off = (i * (2 * DD - i + 1)) / 2 + (j0e - i);
            *reinterpret_cast<float4*>(ob + off) = make_float4(v[0], v[1], v[2], v[3]);
        } else {
            #pragma unroll
            for (int r = 0; r < 4; ++r) {
                const int j = j0e + r;
                if (j >= i) {
                    const int off = (i * (2 * DD - i + 1)) / 2 + (j - i);
                    ob[off] = v[r];
                }
            }
        }
    }
}

extern "C" void kernel_launch(void* const* d_in, const int* in_sizes, int n_in,
                              void* d_out, int out_size, void* d_ws, size_t ws_size,
                              hipStream_t stream) {
    const float* f    = (const float*)d_in[0];
    const float* temp = (const float*)d_in[1];
    float* out  = (float*)d_out;
    float* part = (float*)d_ws;                  // 640*128 f32 = 328 KB
    u32* ctr = (u32*)(part + NTILE * 128);       // 64 u32

    hipMemsetAsync(ctr, 0, NB * sizeof(u32), stream);   // ws not re-poisoned per replay
    k_fused<<<NTILE, 256, 0, stream>>>(f, temp, part, ctr, out);
}

// Round 11
// 36.171 us; speedup vs baseline: 1.7749x; 1.7749x over previous
//
#include <hip/hip_runtime.h>

// B=64, D=256, M=100
//   k(b,i,j) = sum_m sign(f_i)sign(f_j)min(|f_i|,|f_j|) * exp(T)   [0.5 absorbed]
//   out = k - rowmean_i - rowmean_j (symmetric), triu-packed per batch.
// Two kernels (any cross-block sync = 30-130us on MI355X; rounds 7/8/10).
// Pass1: 1280 blocks = (tile, col-half): 64x32 half-tile, full M, fdot2 packed
// fp16 loop, 5 blocks/CU exactly (balanced, 5 waves/SIMD). Pass2: center+pack.

#define NB 64
#define DD 256
#define MM 100
#define TILE 64
#define NUT 10                 // upper 64x64 tile-pairs of the 4x4 tile grid
#define TRI_PER_B 32896        // D*(D+1)/2
#define NTILE 640              // NB * NUT
#define NM2 50                 // fp16x2 m-pairs (full M)
#define TILE_F (TILE * TILE)
#define PSTRIDE 192            // per-tile part floats: rowp[2][64] + colp[64]

typedef unsigned int u32;
typedef _Float16 f16x2 __attribute__((ext_vector_type(2)));
typedef _Float16 f16x4 __attribute__((ext_vector_type(4)));

__device__ __forceinline__ void tile_coords(int t, int& ti, int& tj) {
    int a = (t >= 4) + (t >= 7) + (t >= 9);
    int s = (a * (9 - a)) >> 1;   // 0,4,7,9
    ti = a;
    tj = t - s + a;
}

// For row-group g, the 4 (ut, side) slots covering its row sums.
// byte = ut | (side<<5): g0:{0A,1A,2A,3A} g1:{4A,5A,6A,1B} g2:{7A,8A,2B,5B} g3:{9A,3B,6B,8B}
__device__ __forceinline__ u32 slot_enc(int g) {
    return g == 0 ? 0x03020100u : g == 1 ? 0x21060504u
         : g == 2 ? 0x25220807u : 0x28262309u;
}

// finalize: XCD x gets 80 consecutive tiles = 8 whole batches
__device__ __forceinline__ int swz_bt(int w) { return (w & 7) * 80 + (w >> 3); }

extern "C" __global__ void __launch_bounds__(256, 5)
k_partial(const float* __restrict__ f, float* __restrict__ part,
          _Float16* __restrict__ tiles) {
    __shared__ u32 As[NM2][TILE];   // 12.8 KB
    __shared__ u32 Bs[NM2][32];     // 6.4 KB  (19.2 KB total -> 5 blocks/CU)
    const int t = threadIdx.x;
    // XCD-local mapping: unit = xcd*160 + idx; both halves of a tile and all
    // 8 batches of an XCD stay on that XCD (f rows L2-resident).
    const int unit = (blockIdx.x & 7) * 160 + (blockIdx.x >> 3);  // 0..1279
    const int bt = unit >> 1;        // tile 0..639
    const int half = unit & 1;       // col half
    const int b = bt / NUT;
    const int ut = bt % NUT;
    int ti, tj;
    tile_coords(ut, ti, tj);
    const int i0 = ti * TILE;
    const int j0 = tj * TILE + half * 32;       // this block's 32 cols
    const float* fb = f + (size_t)b * DD * MM;

    // stage A (64 rows) and B (32 rows) as packed fp16 [m2][row]
    for (int l = t; l < TILE * 25; l += 256) {  // 1600 float4
        const int il = l & 63;
        const int mq = l >> 6;
        float4 v = *reinterpret_cast<const float4*>(fb + (size_t)(i0 + il) * MM + mq * 4);
        As[2 * mq + 0][il] = __builtin_bit_cast(u32, __builtin_amdgcn_cvt_pkrtz(v.x, v.y));
        As[2 * mq + 1][il] = __builtin_bit_cast(u32, __builtin_amdgcn_cvt_pkrtz(v.z, v.w));
    }
    for (int l = t; l < 32 * 25; l += 256) {    // 800 float4
        const int il = l & 31;
        const int mq = l >> 5;
        float4 w = *reinterpret_cast<const float4*>(fb + (size_t)(j0 + il) * MM + mq * 4);
        Bs[2 * mq + 0][il] = __builtin_bit_cast(u32, __builtin_amdgcn_cvt_pkrtz(w.x, w.y));
        Bs[2 * mq + 1][il] = __builtin_bit_cast(u32, __builtin_amdgcn_cvt_pkrtz(w.z, w.w));
    }
    __syncthreads();

    const int cg = t & 15;    // col group: local cols 2cg,2cg+1 (coalesced stores)
    const int rg = t >> 4;    // row group: rows 4rg..4rg+3
    float acc[4][2] = {};

    // prefetched pipeline over m2
    uint4 af = *reinterpret_cast<const uint4*>(&As[0][rg * 4]);
    uint2 bf = *reinterpret_cast<const uint2*>(&Bs[0][cg * 2]);
    #pragma unroll 5
    for (int m2 = 0; m2 < NM2; ++m2) {
        uint4 an;
        uint2 bn;
        if (m2 + 1 < NM2) {
            an = *reinterpret_cast<const uint4*>(&As[m2 + 1][rg * 4]);
            bn = *reinterpret_cast<const uint2*>(&Bs[m2 + 1][cg * 2]);
        }
        const u32 av[4] = {af.x, af.y, af.z, af.w};
        const u32 bv[2] = {bf.x, bf.y};
        u32 aab[4], aso[4], bab[2], bsg[2];
        #pragma unroll
        for (int q = 0; q < 4; ++q) {
            aab[q] = av[q] & 0x7fff7fffu;                 // |a|
            aso[q] = (av[q] & 0x80008000u) | 0x3c003c00u; // +-1.0 w/ a's sign
        }
        #pragma unroll
        for (int c = 0; c < 2; ++c) {
            bab[c] = bv[c] & 0x7fff7fffu;
            bsg[c] = bv[c] & 0x80008000u;
        }
        #pragma unroll
        for (int q = 0; q < 4; ++q) {
            #pragma unroll
            for (int c = 0; c < 2; ++c) {
                u32 so = aso[q] ^ bsg[c];                 // +-1.0 product sign
                f16x2 mn = __builtin_elementwise_min(
                    __builtin_bit_cast(f16x2, aab[q]),
                    __builtin_bit_cast(f16x2, bab[c]));   // v_pk_min_f16
                acc[q][c] = __builtin_amdgcn_fdot2(
                    mn, __builtin_bit_cast(f16x2, so), acc[q][c], false);
            }
        }
        af = an; bf = bn;
    }

    // half-tile -> ws as f16; lanes (cg) contiguous -> coalesced 64B/16 lanes
    _Float16* tp = tiles + (size_t)bt * TILE_F;
    #pragma unroll
    for (int q = 0; q < 4; ++q) {
        *reinterpret_cast<u32*>(tp + (rg * 4 + q) * TILE + half * 32 + cg * 2) =
            __builtin_bit_cast(u32, __builtin_amdgcn_cvt_pkrtz(acc[q][0], acc[q][1]));
    }

    // row partials (4 rows x 2 cols summed) and col partials (2 cols x 4 rows)
    float ra[4], cb[2];
    #pragma unroll
    for (int q = 0; q < 4; ++q) ra[q] = acc[q][0] + acc[q][1];
    #pragma unroll
    for (int c = 0; c < 2; ++c)
        cb[c] = (acc[0][c] + acc[1][c]) + (acc[2][c] + acc[3][c]);

    __syncthreads();                       // staging reads done; reuse As
    float* red  = reinterpret_cast<float*>(&As[0][0]);   // [16 cg][64 rows]
    float* red2 = red + 1024;                            // [16 rg][32 cols]
    #pragma unroll
    for (int q = 0; q < 4; ++q) red[cg * 64 + rg * 4 + q] = ra[q];
    #pragma unroll
    for (int c = 0; c < 2; ++c) red2[rg * 32 + cg * 2 + c] = cb[c];
    __syncthreads();

    float* pb = part + (size_t)bt * PSTRIDE;
    if (t < TILE) {                          // row partials for this half
        float s = 0.f;
        #pragma unroll
        for (int w = 0; w < 16; ++w) s += red[w * 64 + t];
        pb[half * 64 + t] = s;
    } else if (t < TILE + 32 && ti != tj) {  // col partials (owned by half)
        const int u = t - TILE;
        float s = 0.f;
        #pragma unroll
        for (int w = 0; w < 16; ++w) s += red2[w * 32 + u];
        pb[128 + half * 32 + u] = s;
    }
}

// Pass 2: reconstruct row sums from part, center, scale, triu-pack.
extern "C" __global__ void __launch_bounds__(256)
k_finalize(const float* __restrict__ part, const float* __restrict__ temp,
           const _Float16* __restrict__ tiles, float* __restrict__ out) {
    __shared__ float rows_sh[128];
    const int t = threadIdx.x;
    const int bt = swz_bt(blockIdx.x);   // 0..639
    const int b = bt / NUT;
    const int ut = bt % NUT;
    int ti, tj;
    tile_coords(ut, ti, tj);
    const int i0 = ti * TILE, j0 = tj * TILE;
    const int tix = t >> 4, tiy = t & 15;

    // rebuild the 128 row sums this tile needs
    if (t < 128) {
        const int hr = t >> 6, u = t & 63;
        const int g = hr ? tj : ti;
        const u32 enc = slot_enc(g);
        float sum = 0.f;
        #pragma unroll
        for (int s = 0; s < 4; ++s) {
            const u32 byte = (enc >> (8 * s)) & 0xffu;
            const int ut_s = byte & 0x1f;
            const int side = byte >> 5;
            const float* pb = part + (size_t)(b * NUT + ut_s) * PSTRIDE;
            sum += side ? pb[128 + u] : (pb[u] + pb[64 + u]);
        }
        rows_sh[t] = sum;
    }

    const _Float16* tp = tiles + (size_t)bt * TILE_F;
    float acc[4][4];
    #pragma unroll
    for (int q = 0; q < 4; ++q) {
        f16x4 v = *reinterpret_cast<const f16x4*>(tp + (tix * 4 + q) * TILE + tiy * 4);
        acc[q][0] = (float)v.x; acc[q][1] = (float)v.y;
        acc[q][2] = (float)v.z; acc[q][3] = (float)v.w;
    }
    __syncthreads();

    const float scale = expf(temp[0]);   // 0.5 absorbed by sign-min identity
    const float inv_d = 1.0f / DD;
    const int cbase = (ti == tj) ? 0 : 64;
    float rloc[4], cloc[4];
    #pragma unroll
    for (int q = 0; q < 4; ++q) rloc[q] = rows_sh[tix * 4 + q];
    #pragma unroll
    for (int r = 0; r < 4; ++r) cloc[r] = rows_sh[cbase + tiy * 4 + r];

    float* ob = out + (size_t)b * TRI_PER_B;
    #pragma unroll
    for (int q = 0; q < 4; ++q) {
        const int i = i0 + tix * 4 + q;
        float v[4];
        #pragma unroll
        for (int r = 0; r < 4; ++r)
            v[r] = scale * (acc[q][r] - (rloc[q] + cloc[r]) * inv_d);
        const int j0e = j0 + tiy * 4;
        if (ti != tj) {
            const int off = (i * (2 * DD - i + 1)) / 2 + (j0e - i);
            *reinterpret_cast<float4*>(ob + off) = make_float4(v[0], v[1], v[2], v[3]);
        } else {
            #pragma unroll
            for (int r = 0; r < 4; ++r) {
                const int j = j0e + r;
                if (j >= i) {
                    const int off = (i * (2 * DD - i + 1)) / 2 + (j - i);
                    ob[off] = v[r];
                }
            }
        }
    }
}

extern "C" void kernel_launch(void* const* d_in, const int* in_sizes, int n_in,
                              void* d_out, int out_size, void* d_ws, size_t ws_size,
                              hipStream_t stream) {
    const float* f    = (const float*)d_in[0];
    const float* temp = (const float*)d_in[1];
    float* out  = (float*)d_out;
    float* part = (float*)d_ws;                           // 640*192 f32 = 491 KB
    _Float16* tiles = (_Float16*)(part + NTILE * PSTRIDE); // 640*4096 f16 = 5.25 MB

    k_partial<<<2 * NTILE, 256, 0, stream>>>(f, part, tiles);
    k_finalize<<<NTILE, 256, 0, stream>>>(part, temp, tiles, out);
}

// Round 12
// 35.812 us; speedup vs baseline: 1.7926x; 1.0100x over previous
//
#include <hip/hip_runtime.h>

// B=64, D=256, M=100
//   k(b,i,j) = sum_m sign(f_i)sign(f_j)min(|f_i|,|f_j|) * exp(T)   [0.5 absorbed]
//   out = k - rowmean_i - rowmean_j (symmetric), triu-packed per batch.
// Two kernels (cross-block sync = 30-130us on MI355X; rounds 7/8/10).
// Pass1: 1280 blocks (tile x col-half), 64x32 half-tile, full M, fdot2 packed
// fp16 loop. Wave-STAGGERED m-chunks de-correlate LDS bursts from VALU phases
// (round-2 counters: VALUBusy 56% + LDS ~42% = 98% -> lockstep serialization).
// Pass2: 1280 blocks center + triu-pack.

#define NB 64
#define DD 256
#define MM 100
#define TILE 64
#define NUT 10                 // upper 64x64 tile-pairs of the 4x4 tile grid
#define TRI_PER_B 32896        // D*(D+1)/2
#define NTILE 640              // NB * NUT
#define NMQ 25                 // mq groups; each mq = 2 m2-pairs = 4 m values
#define TILE_F (TILE * TILE)
#define PSTRIDE 192            // per-tile part floats: rowp[2][64] + colp[64]

typedef unsigned int u32;
typedef _Float16 f16x2 __attribute__((ext_vector_type(2)));

__device__ __forceinline__ void tile_coords(int t, int& ti, int& tj) {
    int a = (t >= 4) + (t >= 7) + (t >= 9);
    int s = (a * (9 - a)) >> 1;   // 0,4,7,9
    ti = a;
    tj = t - s + a;
}

// For row-group g, the 4 (ut, side) slots covering its row sums.
// byte = ut | (side<<5): g0:{0A,1A,2A,3A} g1:{4A,5A,6A,1B} g2:{7A,8A,2B,5B} g3:{9A,3B,6B,8B}
__device__ __forceinline__ u32 slot_enc(int g) {
    return g == 0 ? 0x03020100u : g == 1 ? 0x21060504u
         : g == 2 ? 0x25220807u : 0x28262309u;
}

extern "C" __global__ void __launch_bounds__(256, 5)
k_partial(const float* __restrict__ f, float* __restrict__ part,
          _Float16* __restrict__ tiles) {
    __shared__ u32 As[NMQ][TILE][2];   // 12.8 KB: [mq][row][m2-pair]
    __shared__ u32 Bs[NMQ][32][2];     // 6.4 KB  (19.2 total -> 5 blocks/CU)
    const int t = threadIdx.x;
    // XCD-local mapping: both halves of a tile + 8 whole batches per XCD.
    const int unit = (blockIdx.x & 7) * 160 + (blockIdx.x >> 3);  // 0..1279
    const int bt = unit >> 1;        // tile 0..639
    const int half = unit & 1;       // col half
    const int b = bt / NUT;
    const int ut = bt % NUT;
    int ti, tj;
    tile_coords(ut, ti, tj);
    const int i0 = ti * TILE;
    const int j0 = tj * TILE + half * 32;
    const float* fb = f + (size_t)b * DD * MM;

    // stage A (64 rows) / B (32 rows): float4 -> 2x packed fp16 -> ds_write_b64
    for (int l = t; l < TILE * NMQ; l += 256) {   // 1600 float4
        const int il = l & 63;
        const int mq = l >> 6;
        float4 v = *reinterpret_cast<const float4*>(fb + (size_t)(i0 + il) * MM + mq * 4);
        uint2 p;
        p.x = __builtin_bit_cast(u32, __builtin_amdgcn_cvt_pkrtz(v.x, v.y));
        p.y = __builtin_bit_cast(u32, __builtin_amdgcn_cvt_pkrtz(v.z, v.w));
        *reinterpret_cast<uint2*>(&As[mq][il][0]) = p;
    }
    for (int l = t; l < 32 * NMQ; l += 256) {     // 800 float4
        const int il = l & 31;
        const int mq = l >> 5;
        float4 w = *reinterpret_cast<const float4*>(fb + (size_t)(j0 + il) * MM + mq * 4);
        uint2 p;
        p.x = __builtin_bit_cast(u32, __builtin_amdgcn_cvt_pkrtz(w.x, w.y));
        p.y = __builtin_bit_cast(u32, __builtin_amdgcn_cvt_pkrtz(w.z, w.w));
        *reinterpret_cast<uint2*>(&Bs[mq][il][0]) = p;
    }
    __syncthreads();

    const int cg = t & 15;    // col group: local cols 2cg,2cg+1
    const int rg = t >> 4;    // row group: rows 4rg..4rg+3
    float acc[4][2] = {};

    // wave+block staggered chunk order: 5 chunks x 5 mq
    const int c0 = (int)(((t >> 6) + blockIdx.x) % 5u);
    for (int cc = 0; cc < 5; ++cc) {
        int ch = c0 + cc;
        if (ch >= 5) ch -= 5;
        const int mqb = ch * 5;
        #pragma unroll
        for (int k = 0; k < 5; ++k) {
            const int mq = mqb + k;
            uint4 alo = *reinterpret_cast<const uint4*>(&As[mq][rg * 4 + 0][0]);
            uint4 ahi = *reinterpret_cast<const uint4*>(&As[mq][rg * 4 + 2][0]);
            uint4 bb  = *reinterpret_cast<const uint4*>(&Bs[mq][cg * 2][0]);
            const u32 al[4] = {alo.x, alo.y, alo.z, alo.w};
            const u32 ah[4] = {ahi.x, ahi.y, ahi.z, ahi.w};
            const u32 bl[4] = {bb.x, bb.y, bb.z, bb.w};
            #pragma unroll
            for (int e = 0; e < 2; ++e) {          // the 2 m2-pairs of this mq
                const u32 av[4] = {al[e], al[2 + e], ah[e], ah[2 + e]};
                const u32 bv[2] = {bl[e], bl[2 + e]};
                u32 aab[4], aso[4], bab[2], bsg[2];
                #pragma unroll
                for (int q = 0; q < 4; ++q) {
                    aab[q] = av[q] & 0x7fff7fffu;                 // |a|
                    aso[q] = (av[q] & 0x80008000u) | 0x3c003c00u; // +-1 w/ a sign
                }
                #pragma unroll
                for (int c = 0; c < 2; ++c) {
                    bab[c] = bv[c] & 0x7fff7fffu;
                    bsg[c] = bv[c] & 0x80008000u;
                }
                #pragma unroll
                for (int q = 0; q < 4; ++q) {
                    #pragma unroll
                    for (int c = 0; c < 2; ++c) {
                        u32 so = aso[q] ^ bsg[c];
                        f16x2 mn = __builtin_elementwise_min(
                            __builtin_bit_cast(f16x2, aab[q]),
                            __builtin_bit_cast(f16x2, bab[c]));   // v_pk_min_f16
                        acc[q][c] = __builtin_amdgcn_fdot2(
                            mn, __builtin_bit_cast(f16x2, so), acc[q][c], false);
                    }
                }
            }
        }
    }

    // half-tile -> ws as f16; cg-lanes contiguous -> coalesced
    _Float16* tp = tiles + (size_t)bt * TILE_F;
    #pragma unroll
    for (int q = 0; q < 4; ++q) {
        *reinterpret_cast<u32*>(tp + (rg * 4 + q) * TILE + half * 32 + cg * 2) =
            __builtin_bit_cast(u32, __builtin_amdgcn_cvt_pkrtz(acc[q][0], acc[q][1]));
    }

    // row partials (4 rows) and col partials (2 cols)
    float ra[4], cb[2];
    #pragma unroll
    for (int q = 0; q < 4; ++q) ra[q] = acc[q][0] + acc[q][1];
    #pragma unroll
    for (int c = 0; c < 2; ++c)
        cb[c] = (acc[0][c] + acc[1][c]) + (acc[2][c] + acc[3][c]);

    __syncthreads();                       // staging reads done; reuse As
    float* red  = reinterpret_cast<float*>(&As[0][0][0]);   // [16 cg][64 rows]
    float* red2 = red + 1024;                               // [16 rg][32 cols]
    #pragma unroll
    for (int q = 0; q < 4; ++q) red[cg * 64 + rg * 4 + q] = ra[q];
    #pragma unroll
    for (int c = 0; c < 2; ++c) red2[rg * 32 + cg * 2 + c] = cb[c];
    __syncthreads();

    float* pb = part + (size_t)bt * PSTRIDE;
    if (t < TILE) {                          // row partials for this half
        float s = 0.f;
        #pragma unroll
        for (int w = 0; w < 16; ++w) s += red[w * 64 + t];
        pb[half * 64 + t] = s;
    } else if (t < TILE + 32 && ti != tj) {  // col partials (half-owned)
        const int u = t - TILE;
        float s = 0.f;
        #pragma unroll
        for (int w = 0; w < 16; ++w) s += red2[w * 32 + u];
        pb[128 + half * 32 + u] = s;
    }
}

// Pass 2: 1280 blocks (tile x col-half): row-sum gather, center, triu-pack.
extern "C" __global__ void __launch_bounds__(256)
k_finalize(const float* __restrict__ part, const float* __restrict__ temp,
           const _Float16* __restrict__ tiles, float* __restrict__ out) {
    __shared__ float rows_sh[128];   // [0..63] tile rows, [64..95] half cols
    const int t = threadIdx.x;
    const int unit = (blockIdx.x & 7) * 160 + (blockIdx.x >> 3);
    const int bt = unit >> 1;
    const int half = unit & 1;
    const int b = bt / NUT;
    const int ut = bt % NUT;
    int ti, tj;
    tile_coords(ut, ti, tj);
    const int i0 = ti * TILE, j0 = tj * TILE + half * 32;
    const int tix = t >> 4, tiy = t & 15;

    if (t < 96) {
        const int isrow = (t < 64);
        const int u = isrow ? t : (half * 32 + (t - 64));   // index in 64-row blk
        const int g = isrow ? ti : tj;
        const u32 enc = slot_enc(g);
        float sum = 0.f;
        #pragma unroll
        for (int s = 0; s < 4; ++s) {
            const u32 byte = (enc >> (8 * s)) & 0xffu;
            const int ut_s = byte & 0x1f;
            const int side = byte >> 5;
            const float* pb = part + (size_t)(b * NUT + ut_s) * PSTRIDE;
            sum += side ? pb[128 + u] : (pb[u] + pb[64 + u]);
        }
        rows_sh[t] = sum;
    }

    const _Float16* tp = tiles + (size_t)bt * TILE_F;
    float vv[4][2];
    #pragma unroll
    for (int q = 0; q < 4; ++q) {
        u32 w = *reinterpret_cast<const u32*>(
            tp + (tix * 4 + q) * TILE + half * 32 + tiy * 2);
        f16x2 hv = __builtin_bit_cast(f16x2, w);
        vv[q][0] = (float)hv.x;
        vv[q][1] = (float)hv.y;
    }
    __syncthreads();

    const float scale = expf(temp[0]);   // 0.5 absorbed by sign-min identity
    const float inv_d = 1.0f / DD;
    float rloc[4], cloc[2];
    #pragma unroll
    for (int q = 0; q < 4; ++q) rloc[q] = rows_sh[tix * 4 + q];
    #pragma unroll
    for (int c = 0; c < 2; ++c) {
        const int lc = tiy * 2 + c;      // local col within half
        cloc[c] = (ti == tj) ? rows_sh[half * 32 + lc] : rows_sh[64 + lc];
    }

    float* ob = out + (size_t)b * TRI_PER_B;
    #pragma unroll
    for (int q = 0; q < 4; ++q) {
        const int i = i0 + tix * 4 + q;
        const int j0e = j0 + tiy * 2;
        float v0 = scale * (vv[q][0] - (rloc[q] + cloc[0]) * inv_d);
        float v1 = scale * (vv[q][1] - (rloc[q] + cloc[1]) * inv_d);
        if (ti != tj) {
            const int off = (i * (2 * DD - i + 1)) / 2 + (j0e - i);
            *reinterpret_cast<float2*>(ob + off) = make_float2(v0, v1);
        } else {
            if (j0e >= i)     ob[(i * (2 * DD - i + 1)) / 2 + (j0e - i)]     = v0;
            if (j0e + 1 >= i) ob[(i * (2 * DD - i + 1)) / 2 + (j0e + 1 - i)] = v1;
        }
    }
}

extern "C" void kernel_launch(void* const* d_in, const int* in_sizes, int n_in,
                              void* d_out, int out_size, void* d_ws, size_t ws_size,
                              hipStream_t stream) {
    const float* f    = (const float*)d_in[0];
    const float* temp = (const float*)d_in[1];
    float* out  = (float*)d_out;
    float* part = (float*)d_ws;                            // 640*192 f32 = 491 KB
    _Float16* tiles = (_Float16*)(part + NTILE * PSTRIDE); // 640*4096 f16 = 5.25 MB

    k_partial<<<2 * NTILE, 256, 0, stream>>>(f, part, tiles);
    k_finalize<<<2 * NTILE, 256, 0, stream>>>(part, temp, tiles, out);
}

// Round 13
// 35.726 us; speedup vs baseline: 1.7970x; 1.0024x over previous
//
#include <hip/hip_runtime.h>

// B=64, D=256, M=100
//   k(b,i,j) = sum_m sign(f_i)sign(f_j)min(|f_i|,|f_j|) * exp(T)   [0.5 absorbed]
//   out = k - rowmean_i - rowmean_j (symmetric), triu-packed per batch.
// Two kernels (cross-block sync = 30-130us on MI355X; rounds 7/8/10).
// Pass1: 640 blocks x 512 threads (8 waves -> 5 waves/SIMD TLP, vs 2.5 at 256):
//   full-M 64x64 tile, fdot2 packed-fp16 loop, 4x2 micro-tile.
// Pass2: 1280 blocks center + triu-pack.

#define NB 64
#define DD 256
#define MM 100
#define TILE 64
#define NUT 10                 // upper 64x64 tile-pairs of the 4x4 tile grid
#define TRI_PER_B 32896        // D*(D+1)/2
#define NTILE 640              // NB * NUT
#define NM2 50                 // fp16x2 m-pairs (full M)
#define TILE_F (TILE * TILE)

typedef unsigned int u32;
typedef _Float16 f16x2 __attribute__((ext_vector_type(2)));

__device__ __forceinline__ void tile_coords(int t, int& ti, int& tj) {
    int a = (t >= 4) + (t >= 7) + (t >= 9);
    int s = (a * (9 - a)) >> 1;   // 0,4,7,9
    ti = a;
    tj = t - s + a;
}

// For row-group g, the 4 (ut, side) slots covering its row sums.
// byte = ut | (side<<5): g0:{0A,1A,2A,3A} g1:{4A,5A,6A,1B} g2:{7A,8A,2B,5B} g3:{9A,3B,6B,8B}
__device__ __forceinline__ u32 slot_enc(int g) {
    return g == 0 ? 0x03020100u : g == 1 ? 0x21060504u
         : g == 2 ? 0x25220807u : 0x28262309u;
}

// XCD-local tile mapping: XCD x gets 80 consecutive tiles = 8 whole batches.
__device__ __forceinline__ int swz_bt(int w) { return (w & 7) * 80 + (w >> 3); }

extern "C" __global__ void __launch_bounds__(512, 5)
k_partial(const float* __restrict__ f, float* __restrict__ part,
          _Float16* __restrict__ tiles) {
    __shared__ u32 As[NM2][TILE];   // 12.8 KB  [m2][row]
    __shared__ u32 Bs[NM2][TILE];   // 12.8 KB  (25.6 total; 2.5 blk/CU = 64 KB)
    const int t = threadIdx.x;
    const int bt = swz_bt(blockIdx.x);   // 0..639
    const int b = bt / NUT;
    const int ut = bt % NUT;
    int ti, tj;
    tile_coords(ut, ti, tj);
    const int i0 = ti * TILE, j0 = tj * TILE;
    const float* fb = f + (size_t)b * DD * MM;

    // ---- stage full M as packed fp16, layout [m2][row] ----
    for (int l = t; l < TILE * 25; l += 512) {   // 1600 float4 per matrix
        const int il = l & 63;
        const int mq = l >> 6;                   // 0..24
        float4 v = *reinterpret_cast<const float4*>(fb + (size_t)(i0 + il) * MM + mq * 4);
        As[2 * mq + 0][il] = __builtin_bit_cast(u32, __builtin_amdgcn_cvt_pkrtz(v.x, v.y));
        As[2 * mq + 1][il] = __builtin_bit_cast(u32, __builtin_amdgcn_cvt_pkrtz(v.z, v.w));
        float4 w = *reinterpret_cast<const float4*>(fb + (size_t)(j0 + il) * MM + mq * 4);
        Bs[2 * mq + 0][il] = __builtin_bit_cast(u32, __builtin_amdgcn_cvt_pkrtz(w.x, w.y));
        Bs[2 * mq + 1][il] = __builtin_bit_cast(u32, __builtin_amdgcn_cvt_pkrtz(w.z, w.w));
    }
    __syncthreads();

    // 4x2 micro-tile: rows rg*4..+3 (rg=t>>5, 0..15), cols cg*2..+1 (cg=t&31)
    const int rg = t >> 5, cg = t & 31;
    float acc[4][2] = {};

    #pragma unroll 5
    for (int m2 = 0; m2 < NM2; ++m2) {
        uint4 afu = *reinterpret_cast<const uint4*>(&As[m2][rg * 4]);  // b128 bcast
        uint2 bfu = *reinterpret_cast<const uint2*>(&Bs[m2][cg * 2]);  // b64
        const u32 av[4] = {afu.x, afu.y, afu.z, afu.w};
        const u32 bv[2] = {bfu.x, bfu.y};
        u32 aab[4], aso[4], bab[2], bsg[2];
        #pragma unroll
        for (int q = 0; q < 4; ++q) {
            aab[q] = av[q] & 0x7fff7fffu;                 // |a|
            aso[q] = (av[q] & 0x80008000u) | 0x3c003c00u; // +-1.0 w/ a's sign
        }
        #pragma unroll
        for (int c = 0; c < 2; ++c) {
            bab[c] = bv[c] & 0x7fff7fffu;
            bsg[c] = bv[c] & 0x80008000u;
        }
        #pragma unroll
        for (int q = 0; q < 4; ++q) {
            #pragma unroll
            for (int c = 0; c < 2; ++c) {
                u32 so = aso[q] ^ bsg[c];                 // +-1.0 product sign
                f16x2 mn = __builtin_elementwise_min(
                    __builtin_bit_cast(f16x2, aab[q]),
                    __builtin_bit_cast(f16x2, bab[c]));   // v_pk_min_f16
                acc[q][c] = __builtin_amdgcn_fdot2(
                    mn, __builtin_bit_cast(f16x2, so), acc[q][c], false);
            }
        }
    }

    // tile -> ws as f16; cg-lanes contiguous -> coalesced 128B per 32 lanes
    _Float16* tp = tiles + (size_t)bt * TILE_F;
    #pragma unroll
    for (int q = 0; q < 4; ++q) {
        *reinterpret_cast<u32*>(tp + (rg * 4 + q) * TILE + cg * 2) =
            __builtin_bit_cast(u32, __builtin_amdgcn_cvt_pkrtz(acc[q][0], acc[q][1]));
    }

    // row partials (4 rows) / col partials (2 cols)
    float ra[4], cb[2];
    #pragma unroll
    for (int q = 0; q < 4; ++q) ra[q] = acc[q][0] + acc[q][1];
    #pragma unroll
    for (int c = 0; c < 2; ++c)
        cb[c] = (acc[0][c] + acc[1][c]) + (acc[2][c] + acc[3][c]);

    __syncthreads();                       // staging reads done; reuse As
    float* red  = reinterpret_cast<float*>(&As[0][0]);   // [32 cg][64 rows] 8KB
    float* red2 = red + 2048;                            // [16 rg][64 cols] 4KB
    #pragma unroll
    for (int q = 0; q < 4; ++q) red[cg * 64 + rg * 4 + q] = ra[q];
    #pragma unroll
    for (int c = 0; c < 2; ++c) red2[rg * 64 + cg * 2 + c] = cb[c];
    __syncthreads();

    float* pb = part + (size_t)bt * 128;
    if (t < TILE) {                          // row sums
        float s = 0.f;
        #pragma unroll
        for (int w = 0; w < 32; ++w) s += red[w * 64 + t];
        pb[t] = s;
    } else if (t < 2 * TILE && ti != tj) {   // col sums (off-diag only)
        const int u = t - TILE;
        float s = 0.f;
        #pragma unroll
        for (int w = 0; w < 16; ++w) s += red2[w * 64 + u];
        pb[64 + u] = s;
    }
}

// Pass 2: 1280 blocks (tile x col-half): row-sum gather, center, triu-pack.
extern "C" __global__ void __launch_bounds__(256)
k_finalize(const float* __restrict__ part, const float* __restrict__ temp,
           const _Float16* __restrict__ tiles, float* __restrict__ out) {
    __shared__ float rows_sh[96];   // [0..63] tile rows, [64..95] this half's cols
    const int t = threadIdx.x;
    const int unit = (blockIdx.x & 7) * 160 + (blockIdx.x >> 3);  // 0..1279
    const int bt = unit >> 1;
    const int half = unit & 1;
    const int b = bt / NUT;
    const int ut = bt % NUT;
    int ti, tj;
    tile_coords(ut, ti, tj);
    const int i0 = ti * TILE, j0 = tj * TILE + half * 32;
    const int tix = t >> 4, tiy = t & 15;

    if (t < 96) {
        const int isrow = (t < 64);
        const int u = isrow ? t : (half * 32 + (t - 64));
        const int g = isrow ? ti : tj;
        const u32 enc = slot_enc(g);
        float sum = 0.f;
        #pragma unroll
        for (int s = 0; s < 4; ++s) {
            const u32 byte = (enc >> (8 * s)) & 0xffu;
            const int ut_s = byte & 0x1f;
            const int side = byte >> 5;
            sum += part[(size_t)(b * NUT + ut_s) * 128 + side * 64 + u];
        }
        rows_sh[t] = sum;
    }

    const _Float16* tp = tiles + (size_t)bt * TILE_F;
    float vv[4][2];
    #pragma unroll
    for (int q = 0; q < 4; ++q) {
        u32 w = *reinterpret_cast<const u32*>(
            tp + (tix * 4 + q) * TILE + half * 32 + tiy * 2);
        f16x2 hv = __builtin_bit_cast(f16x2, w);
        vv[q][0] = (float)hv.x;
        vv[q][1] = (float)hv.y;
    }
    __syncthreads();

    const float scale = expf(temp[0]);   // 0.5 absorbed by sign-min identity
    const float inv_d = 1.0f / DD;
    float rloc[4], cloc[2];
    #pragma unroll
    for (int q = 0; q < 4; ++q) rloc[q] = rows_sh[tix * 4 + q];
    #pragma unroll
    for (int c = 0; c < 2; ++c) {
        const int lc = tiy * 2 + c;          // local col within this half
        cloc[c] = (ti == tj) ? rows_sh[half * 32 + lc] : rows_sh[64 + lc];
    }

    float* ob = out + (size_t)b * TRI_PER_B;
    #pragma unroll
    for (int q = 0; q < 4; ++q) {
        const int i = i0 + tix * 4 + q;
        const int j0e = j0 + tiy * 2;
        float v0 = scale * (vv[q][0] - (rloc[q] + cloc[0]) * inv_d);
        float v1 = scale * (vv[q][1] - (rloc[q] + cloc[1]) * inv_d);
        if (ti != tj) {
            const int off = (i * (2 * DD - i + 1)) / 2 + (j0e - i);
            *reinterpret_cast<float2*>(ob + off) = make_float2(v0, v1);
        } else {
            if (j0e >= i)     ob[(i * (2 * DD - i + 1)) / 2 + (j0e - i)]     = v0;
            if (j0e + 1 >= i) ob[(i * (2 * DD - i + 1)) / 2 + (j0e + 1 - i)] = v1;
        }
    }
}

extern "C" void kernel_launch(void* const* d_in, const int* in_sizes, int n_in,
                              void* d_out, int out_size, void* d_ws, size_t ws_size,
                              hipStream_t stream) {
    const float* f    = (const float*)d_in[0];
    const float* temp = (const float*)d_in[1];
    float* out  = (float*)d_out;
    float* part = (float*)d_ws;                      // 640*128 f32 = 328 KB
    _Float16* tiles = (_Float16*)(part + NTILE * 128); // 640*4096 f16 = 5.25 MB

    k_partial<<<NTILE, 512, 0, stream>>>(f, part, tiles);
    k_finalize<<<2 * NTILE, 256, 0, stream>>>(part, temp, tiles, out);
}

// Round 14
// 34.671 us; speedup vs baseline: 1.8516x; 1.0304x over previous
//
#include <hip/hip_runtime.h>

// B=64, D=256, M=100
//   k(b,i,j) = sum_m s_i s_j min(|f_i|,|f_j|) * exp(T)      [0.5 absorbed]
//            = sum_m sign(f_j) * clamp(f_i, -|f_j|, |f_j|) * exp(T)
//   out = k - rowmean_i - rowmean_j (symmetric), triu-packed per batch.
// Two kernels (cross-block sync = 30-130us; rounds 7/8/10).
// Pass1: 640 blocks x 512 threads, full-M 64x64 tile. Inner loop uses the
// clamp identity: raw-A (zero row prep) + pk_max(neg-mod)/pk_min/fdot2.
// B staged [mq][col][2] so one b128 feeds two m2-slices. Pass2: center+pack.

#define NB 64
#define DD 256
#define MM 100
#define TILE 64
#define NUT 10                 // upper 64x64 tile-pairs of the 4x4 tile grid
#define TRI_PER_B 32896        // D*(D+1)/2
#define NTILE 640              // NB * NUT
#define NMQ 25                 // m-quads (4 m = 2 m2-slices each)
#define TILE_F (TILE * TILE)

typedef unsigned int u32;
typedef _Float16 f16x2 __attribute__((ext_vector_type(2)));

__device__ __forceinline__ void tile_coords(int t, int& ti, int& tj) {
    int a = (t >= 4) + (t >= 7) + (t >= 9);
    int s = (a * (9 - a)) >> 1;   // 0,4,7,9
    ti = a;
    tj = t - s + a;
}

// For row-group g, the 4 (ut, side) slots covering its row sums.
// byte = ut | (side<<5): g0:{0A,1A,2A,3A} g1:{4A,5A,6A,1B} g2:{7A,8A,2B,5B} g3:{9A,3B,6B,8B}
__device__ __forceinline__ u32 slot_enc(int g) {
    return g == 0 ? 0x03020100u : g == 1 ? 0x21060504u
         : g == 2 ? 0x25220807u : 0x28262309u;
}

// XCD-local tile mapping: XCD x gets 80 consecutive tiles = 8 whole batches.
__device__ __forceinline__ int swz_bt(int w) { return (w & 7) * 80 + (w >> 3); }

extern "C" __global__ void __launch_bounds__(512, 5)
k_partial(const float* __restrict__ f, float* __restrict__ part,
          _Float16* __restrict__ tiles) {
    __shared__ u32 As[2 * NMQ][TILE];    // 12.8 KB  [m2][row]
    __shared__ u32 Bs[NMQ][TILE][2];     // 12.8 KB  [mq][col][m2-slice]
    const int t = threadIdx.x;
    const int bt = swz_bt(blockIdx.x);   // 0..639
    const int b = bt / NUT;
    const int ut = bt % NUT;
    int ti, tj;
    tile_coords(ut, ti, tj);
    const int i0 = ti * TILE, j0 = tj * TILE;
    const float* fb = f + (size_t)b * DD * MM;

    // ---- stage full M as packed fp16 ----
    for (int l = t; l < TILE * NMQ; l += 512) {   // 1600 float4 per matrix
        const int il = l & 63;
        const int mq = l >> 6;                    // 0..24
        float4 v = *reinterpret_cast<const float4*>(fb + (size_t)(i0 + il) * MM + mq * 4);
        As[2 * mq + 0][il] = __builtin_bit_cast(u32, __builtin_amdgcn_cvt_pkrtz(v.x, v.y));
        As[2 * mq + 1][il] = __builtin_bit_cast(u32, __builtin_amdgcn_cvt_pkrtz(v.z, v.w));
        float4 w = *reinterpret_cast<const float4*>(fb + (size_t)(j0 + il) * MM + mq * 4);
        uint2 p;
        p.x = __builtin_bit_cast(u32, __builtin_amdgcn_cvt_pkrtz(w.x, w.y));
        p.y = __builtin_bit_cast(u32, __builtin_amdgcn_cvt_pkrtz(w.z, w.w));
        *reinterpret_cast<uint2*>(&Bs[mq][il][0]) = p;   // ds_write_b64
    }
    __syncthreads();

    // 4x2 micro-tile: rows rg*4..+3 (rg=t>>5), cols cg*2..+1 (cg=t&31)
    const int rg = t >> 5, cg = t & 31;
    float acc[4][2] = {};

    #pragma unroll 5
    for (int mq = 0; mq < NMQ; ++mq) {
        uint4 a0 = *reinterpret_cast<const uint4*>(&As[2 * mq + 0][rg * 4]); // b128
        uint4 a1 = *reinterpret_cast<const uint4*>(&As[2 * mq + 1][rg * 4]); // b128
        uint4 bb = *reinterpret_cast<const uint4*>(&Bs[mq][cg * 2][0]);      // b128
        // bb = {col0 m2e, col0 m2o, col1 m2e, col1 m2o}
        const u32 bcol[2][2] = {{bb.x, bb.y}, {bb.z, bb.w}};
        #pragma unroll
        for (int c = 0; c < 2; ++c) {
            #pragma unroll
            for (int e = 0; e < 2; ++e) {         // m2-slice
                const u32 bw  = bcol[c][e];
                const u32 babu = bw & 0x7fff7fffu;                  // |b|
                const u32 bsou = (bw & 0x80008000u) | 0x3c003c00u;  // +-1 w/ b sign
                const f16x2 bab = __builtin_bit_cast(f16x2, babu);
                const f16x2 bso = __builtin_bit_cast(f16x2, bsou);
                const uint4& aa = e ? a1 : a0;
                const u32 av[4] = {aa.x, aa.y, aa.z, aa.w};
                #pragma unroll
                for (int q = 0; q < 4; ++q) {
                    f16x2 a = __builtin_bit_cast(f16x2, av[q]);
                    f16x2 lo = __builtin_elementwise_max(a, -bab);  // neg modifier
                    f16x2 cl = __builtin_elementwise_min(lo, bab);  // clamp
                    acc[q][c] = __builtin_amdgcn_fdot2(cl, bso, acc[q][c], false);
                }
            }
        }
    }

    // tile -> ws as f16; cg-lanes contiguous -> coalesced
    _Float16* tp = tiles + (size_t)bt * TILE_F;
    #pragma unroll
    for (int q = 0; q < 4; ++q) {
        *reinterpret_cast<u32*>(tp + (rg * 4 + q) * TILE + cg * 2) =
            __builtin_bit_cast(u32, __builtin_amdgcn_cvt_pkrtz(acc[q][0], acc[q][1]));
    }

    // row partials (4 rows) / col partials (2 cols)
    float ra[4], cb[2];
    #pragma unroll
    for (int q = 0; q < 4; ++q) ra[q] = acc[q][0] + acc[q][1];
    #pragma unroll
    for (int c = 0; c < 2; ++c)
        cb[c] = (acc[0][c] + acc[1][c]) + (acc[2][c] + acc[3][c]);

    __syncthreads();                       // staging reads done; reuse As
    float* red  = reinterpret_cast<float*>(&As[0][0]);   // [32 cg][64 rows] 8KB
    float* red2 = red + 2048;                            // [16 rg][64 cols] 4KB
    #pragma unroll
    for (int q = 0; q < 4; ++q) red[cg * 64 + rg * 4 + q] = ra[q];
    #pragma unroll
    for (int c = 0; c < 2; ++c) red2[rg * 64 + cg * 2 + c] = cb[c];
    __syncthreads();

    float* pb = part + (size_t)bt * 128;
    if (t < TILE) {                          // row sums
        float s = 0.f;
        #pragma unroll
        for (int w = 0; w < 32; ++w) s += red[w * 64 + t];
        pb[t] = s;
    } else if (t < 2 * TILE && ti != tj) {   // col sums (off-diag only)
        const int u = t - TILE;
        float s = 0.f;
        #pragma unroll
        for (int w = 0; w < 16; ++w) s += red2[w * 64 + u];
        pb[64 + u] = s;
    }
}

// Pass 2: 1280 blocks (tile x col-half): row-sum gather, center, triu-pack.
extern "C" __global__ void __launch_bounds__(256)
k_finalize(const float* __restrict__ part, const float* __restrict__ temp,
           const _Float16* __restrict__ tiles, float* __restrict__ out) {
    __shared__ float rows_sh[96];   // [0..63] tile rows, [64..95] this half's cols
    const int t = threadIdx.x;
    const int unit = (blockIdx.x & 7) * 160 + (blockIdx.x >> 3);  // 0..1279
    const int bt = unit >> 1;
    const int half = unit & 1;
    const int b = bt / NUT;
    const int ut = bt % NUT;
    int ti, tj;
    tile_coords(ut, ti, tj);
    const int i0 = ti * TILE, j0 = tj * TILE + half * 32;
    const int tix = t >> 4, tiy = t & 15;

    if (t < 96) {
        const int isrow = (t < 64);
        const int u = isrow ? t : (half * 32 + (t - 64));
        const int g = isrow ? ti : tj;
        const u32 enc = slot_enc(g);
        float sum = 0.f;
        #pragma unroll
        for (int s = 0; s < 4; ++s) {
            const u32 byte = (enc >> (8 * s)) & 0xffu;
            const int ut_s = byte & 0x1f;
            const int side = byte >> 5;
            sum += part[(size_t)(b * NUT + ut_s) * 128 + side * 64 + u];
        }
        rows_sh[t] = sum;
    }

    const _Float16* tp = tiles + (size_t)bt * TILE_F;
    float vv[4][2];
    #pragma unroll
    for (int q = 0; q < 4; ++q) {
        u32 w = *reinterpret_cast<const u32*>(
            tp + (tix * 4 + q) * TILE + half * 32 + tiy * 2);
        f16x2 hv = __builtin_bit_cast(f16x2, w);
        vv[q][0] = (float)hv.x;
        vv[q][1] = (float)hv.y;
    }
    __syncthreads();

    const float scale = expf(temp[0]);   // 0.5 absorbed by sign-min identity
    const float inv_d = 1.0f / DD;
    float rloc[4], cloc[2];
    #pragma unroll
    for (int q = 0; q < 4; ++q) rloc[q] = rows_sh[tix * 4 + q];
    #pragma unroll
    for (int c = 0; c < 2; ++c) {
        const int lc = tiy * 2 + c;          // local col within this half
        cloc[c] = (ti == tj) ? rows_sh[half * 32 + lc] : rows_sh[64 + lc];
    }

    float* ob = out + (size_t)b * TRI_PER_B;
    #pragma unroll
    for (int q = 0; q < 4; ++q) {
        const int i = i0 + tix * 4 + q;
        const int j0e = j0 + tiy * 2;
        float v0 = scale * (vv[q][0] - (rloc[q] + cloc[0]) * inv_d);
        float v1 = scale * (vv[q][1] - (rloc[q] + cloc[1]) * inv_d);
        if (ti != tj) {
            const int off = (i * (2 * DD - i + 1)) / 2 + (j0e - i);
            *reinterpret_cast<float2*>(ob + off) = make_float2(v0, v1);
        } else {
            if (j0e >= i)     ob[(i * (2 * DD - i + 1)) / 2 + (j0e - i)]     = v0;
            if (j0e + 1 >= i) ob[(i * (2 * DD - i + 1)) / 2 + (j0e + 1 - i)] = v1;
        }
    }
}

extern "C" void kernel_launch(void* const* d_in, const int* in_sizes, int n_in,
                              void* d_out, int out_size, void* d_ws, size_t ws_size,
                              hipStream_t stream) {
    const float* f    = (const float*)d_in[0];
    const float* temp = (const float*)d_in[1];
    float* out  = (float*)d_out;
    float* part = (float*)d_ws;                        // 640*128 f32 = 328 KB
    _Float16* tiles = (_Float16*)(part + NTILE * 128); // 640*4096 f16 = 5.25 MB

    k_partial<<<NTILE, 512, 0, stream>>>(f, part, tiles);
    k_finalize<<<2 * NTILE, 256, 0, stream>>>(part, temp, tiles, out);
}